// Round 1
// baseline (869.414 us; speedup 1.0000x reference)
//
#include <hip/hip_runtime.h>
#include <hip/hip_bf16.h>
#include <math.h>

typedef __hip_bfloat16 bf16_t;
typedef __bf16 bf16x8 __attribute__((ext_vector_type(8)));
typedef float f32x4 __attribute__((ext_vector_type(4)));

// ---------------------------------------------------------------------------
// async global->LDS, 16B per lane. LDS dest = wave-uniform base + lane*16.
__device__ __forceinline__ void load_lds16(const void* g, void* l) {
    __builtin_amdgcn_global_load_lds(
        (__attribute__((address_space(1))) void*)g,
        (__attribute__((address_space(3))) void*)l, 16, 0, 0);
}

// ---------------------------------------------------------------------------
// Weight transpose+convert: W [K,N] fp32 -> Wt [N,K] bf16 (B^T layout for GEMM)
__global__ __launch_bounds__(256) void wconv_kernel(
    const float* __restrict__ W, bf16_t* __restrict__ Wt, int K, int N)
{
    __shared__ float tile[32][33];
    const int k0 = blockIdx.x * 32, n0 = blockIdx.y * 32;
    const int tx = threadIdx.x & 31, ty = threadIdx.x >> 5;  // 32x8
    #pragma unroll
    for (int i = 0; i < 32; i += 8)
        tile[ty + i][tx] = W[(size_t)(k0 + ty + i) * N + n0 + tx];
    __syncthreads();
    #pragma unroll
    for (int i = 0; i < 32; i += 8)
        Wt[(size_t)(n0 + ty + i) * K + k0 + tx] = __float2bfloat16(tile[tx][ty + i]);
}

// ---------------------------------------------------------------------------
__global__ __launch_bounds__(256) void copy_f4_kernel(
    const float4* __restrict__ in, float4* __restrict__ out, int n)
{
    const int i = blockIdx.x * 256 + threadIdx.x;
    if (i < n) out[i] = in[i];
}

// ---------------------------------------------------------------------------
// LayerNorm: fp32 row [768] -> bf16 row. One block per token.
__global__ __launch_bounds__(256) void ln_kernel(
    const float* __restrict__ x, const float* __restrict__ g,
    const float* __restrict__ b, bf16_t* __restrict__ out)
{
    const int t = blockIdx.x;
    const int tid = threadIdx.x;
    const float* xr = x + (size_t)t * 768;
    float v[3], s = 0.f, q = 0.f;
    #pragma unroll
    for (int i = 0; i < 3; ++i) {
        v[i] = xr[tid + i * 256];
        s += v[i]; q += v[i] * v[i];
    }
    #pragma unroll
    for (int o = 32; o > 0; o >>= 1) {
        s += __shfl_down(s, o);
        q += __shfl_down(q, o);
    }
    __shared__ float rs_[4], rq_[4];
    const int w = tid >> 6, lane = tid & 63;
    if (lane == 0) { rs_[w] = s; rq_[w] = q; }
    __syncthreads();
    s = rs_[0] + rs_[1] + rs_[2] + rs_[3];
    q = rq_[0] + rq_[1] + rq_[2] + rq_[3];
    const float mean = s * (1.f / 768.f);
    const float var  = q * (1.f / 768.f) - mean * mean;
    const float rstd = rsqrtf(var + 1e-5f);
    bf16_t* orow = out + (size_t)t * 768;
    #pragma unroll
    for (int i = 0; i < 3; ++i) {
        const int d = tid + i * 256;
        orow[d] = __float2bfloat16((v[i] - mean) * rstd * g[d] + b[d]);
    }
}

// ---------------------------------------------------------------------------
// GEMM: C[M,N] = A[M,K] @ B[K,N] (+bias, +epilogue), A bf16 row-major,
// Bt = B^T [N,K] bf16 row-major. 128x128 tile, BK=32, 4 waves of 64x64.
// mode 0: out bf16 = acc+bias
// mode 1: out bf16 = gelu_exact(acc+bias)
// mode 2: out fp32 = resid + ls*(acc+bias)
__global__ __launch_bounds__(256) void gemm_kernel(
    const bf16_t* __restrict__ A, const bf16_t* __restrict__ Bt,
    const float* __restrict__ bias, const float* __restrict__ ls,
    const float* __restrict__ resid, void* __restrict__ outp,
    int M, int N, int K, int mode)
{
    __shared__ __align__(16) bf16_t As[128 * 32];
    __shared__ __align__(16) bf16_t Bs[128 * 32];
    const int tid  = threadIdx.x;
    const int lane = tid & 63;
    const int w    = tid >> 6;
    const int wm   = w >> 1, wn = w & 1;
    const int l4   = lane & 15, quad = lane >> 4;
    const int bm   = blockIdx.x, bn = blockIdx.y;

    f32x4 acc[4][4];
    #pragma unroll
    for (int i = 0; i < 4; ++i)
        #pragma unroll
        for (int j = 0; j < 4; ++j)
            #pragma unroll
            for (int e = 0; e < 4; ++e) acc[i][j][e] = 0.f;

    const int srow = lane >> 2;        // 0..15 within a 16-row wave span
    const int scol = (lane & 3) * 8;   // element offset in K
    const bf16_t* Ag = A  + (size_t)(bm * 128) * K;
    const bf16_t* Bg = Bt + (size_t)(bn * 128) * K;

    for (int k0 = 0; k0 < K; k0 += 32) {
        #pragma unroll
        for (int p = 0; p < 2; ++p) {
            const int r = p * 64 + w * 16 + srow;
            load_lds16(Ag + (size_t)r * K + k0 + scol, &As[(p * 64 + w * 16) * 32]);
            load_lds16(Bg + (size_t)r * K + k0 + scol, &Bs[(p * 64 + w * 16) * 32]);
        }
        __syncthreads();
        bf16x8 af[4], bfr[4];
        #pragma unroll
        for (int i = 0; i < 4; ++i)
            af[i] = *(const bf16x8*)&As[(wm * 64 + i * 16 + l4) * 32 + quad * 8];
        #pragma unroll
        for (int j = 0; j < 4; ++j)
            bfr[j] = *(const bf16x8*)&Bs[(wn * 64 + j * 16 + l4) * 32 + quad * 8];
        #pragma unroll
        for (int i = 0; i < 4; ++i)
            #pragma unroll
            for (int j = 0; j < 4; ++j)
                acc[i][j] = __builtin_amdgcn_mfma_f32_16x16x32_bf16(
                    af[i], bfr[j], acc[i][j], 0, 0, 0);
        __syncthreads();
    }

    #pragma unroll
    for (int i = 0; i < 4; ++i) {
        #pragma unroll
        for (int j = 0; j < 4; ++j) {
            const int col  = bn * 128 + wn * 64 + j * 16 + l4;
            const int row0 = bm * 128 + wm * 64 + i * 16 + quad * 4;
            const float bc = bias[col];
            #pragma unroll
            for (int r = 0; r < 4; ++r) {
                float v = acc[i][j][r] + bc;
                const size_t idx = (size_t)(row0 + r) * N + col;
                if (mode == 0) {
                    ((bf16_t*)outp)[idx] = __float2bfloat16(v);
                } else if (mode == 1) {
                    v = 0.5f * v * (1.f + erff(v * 0.70710678118654752f));
                    ((bf16_t*)outp)[idx] = __float2bfloat16(v);
                } else {
                    ((float*)outp)[idx] = resid[idx] + ls[col] * v;
                }
            }
        }
    }
}

// ---------------------------------------------------------------------------
// Flash attention: one block per (seq s, head h, 64-query tile qt).
// qkv bf16 [tok][2304]: q @ h*64, k @ 768+h*64, v @ 1536+h*64. Q pre-scaled.
__global__ __launch_bounds__(256) void attn_kernel(
    const bf16_t* __restrict__ qkv, bf16_t* __restrict__ ao,
    int N, int tok_off)
{
    __shared__ __align__(16) bf16_t Qs[64 * 64];
    __shared__ __align__(16) bf16_t Ks[64 * 64];
    __shared__ __align__(16) bf16_t Vts[64 * 64];   // [hd][key]
    __shared__ __align__(16) bf16_t Ps[4 * 16 * 64];
    const int qt = blockIdx.x, h = blockIdx.y, s = blockIdx.z;
    const int tid = threadIdx.x, lane = tid & 63, w = tid >> 6;
    const int l4 = lane & 15, quad = lane >> 4;
    const size_t seq_base = (size_t)(tok_off + s * N) * 2304;
    const int hoff = h * 64;

    // stage Q (scaled by HD^-0.5 = 1/8, exact in bf16)
    for (int e = tid; e < 4096; e += 256) {
        const int r = e >> 6, d = e & 63;
        const size_t gi = seq_base + (size_t)(qt * 64 + r) * 2304 + hoff + d;
        Qs[e] = __float2bfloat16(__bfloat162float(qkv[gi]) * 0.125f);
    }

    f32x4 oacc[4];
    float m_i[4], l_i[4];
    #pragma unroll
    for (int j = 0; j < 4; ++j)
        #pragma unroll
        for (int e = 0; e < 4; ++e) oacc[j][e] = 0.f;
    #pragma unroll
    for (int r = 0; r < 4; ++r) { m_i[r] = -INFINITY; l_i[r] = 0.f; }
    __syncthreads();

    bf16_t* Pw = &Ps[w * 16 * 64];
    const int nkt = N >> 6;
    for (int kt = 0; kt < nkt; ++kt) {
        // stage K tile [key][hd] and V tile transposed [hd][key]
        for (int e = tid; e < 4096; e += 256) {
            const int r = e >> 6, d = e & 63;
            const size_t gb = seq_base + (size_t)(kt * 64 + r) * 2304 + hoff + d;
            Ks[e] = qkv[gb + 768];
            Vts[d * 64 + r] = qkv[gb + 1536];
        }
        __syncthreads();

        // S = Q K^T  (16 queries x 64 keys per wave)
        f32x4 st[4];
        #pragma unroll
        for (int j = 0; j < 4; ++j)
            #pragma unroll
            for (int e = 0; e < 4; ++e) st[j][e] = 0.f;
        const bf16x8 aq0 = *(const bf16x8*)&Qs[(w * 16 + l4) * 64 + quad * 8];
        const bf16x8 aq1 = *(const bf16x8*)&Qs[(w * 16 + l4) * 64 + 32 + quad * 8];
        #pragma unroll
        for (int j = 0; j < 4; ++j) {
            const bf16x8 b0 = *(const bf16x8*)&Ks[(j * 16 + l4) * 64 + quad * 8];
            const bf16x8 b1 = *(const bf16x8*)&Ks[(j * 16 + l4) * 64 + 32 + quad * 8];
            st[j] = __builtin_amdgcn_mfma_f32_16x16x32_bf16(aq0, b0, st[j], 0, 0, 0);
            st[j] = __builtin_amdgcn_mfma_f32_16x16x32_bf16(aq1, b1, st[j], 0, 0, 0);
        }

        // online softmax per query row (row = quad*4+r, cols spread over 16 lanes x 4 tiles)
        float p[4][4];
        #pragma unroll
        for (int r = 0; r < 4; ++r) {
            float mx = fmaxf(fmaxf(st[0][r], st[1][r]), fmaxf(st[2][r], st[3][r]));
            #pragma unroll
            for (int off = 1; off < 16; off <<= 1) mx = fmaxf(mx, __shfl_xor(mx, off));
            const float mnew  = fmaxf(m_i[r], mx);
            const float alpha = __expf(m_i[r] - mnew);
            float rs = 0.f;
            #pragma unroll
            for (int j = 0; j < 4; ++j) { p[j][r] = __expf(st[j][r] - mnew); rs += p[j][r]; }
            #pragma unroll
            for (int off = 1; off < 16; off <<= 1) rs += __shfl_xor(rs, off);
            m_i[r] = mnew;
            l_i[r] = l_i[r] * alpha + rs;
            #pragma unroll
            for (int j = 0; j < 4; ++j) oacc[j][r] *= alpha;
        }

        // P: C-layout -> LDS -> A-layout
        #pragma unroll
        for (int j = 0; j < 4; ++j)
            #pragma unroll
            for (int r = 0; r < 4; ++r)
                Pw[(quad * 4 + r) * 64 + j * 16 + l4] = __float2bfloat16(p[j][r]);
        __syncthreads();

        const bf16x8 ap0 = *(const bf16x8*)&Pw[l4 * 64 + quad * 8];
        const bf16x8 ap1 = *(const bf16x8*)&Pw[l4 * 64 + 32 + quad * 8];
        #pragma unroll
        for (int j = 0; j < 4; ++j) {
            const bf16x8 v0 = *(const bf16x8*)&Vts[(j * 16 + l4) * 64 + quad * 8];
            const bf16x8 v1 = *(const bf16x8*)&Vts[(j * 16 + l4) * 64 + 32 + quad * 8];
            oacc[j] = __builtin_amdgcn_mfma_f32_16x16x32_bf16(ap0, v0, oacc[j], 0, 0, 0);
            oacc[j] = __builtin_amdgcn_mfma_f32_16x16x32_bf16(ap1, v1, oacc[j], 0, 0, 0);
        }
        __syncthreads();
    }

    #pragma unroll
    for (int r = 0; r < 4; ++r) {
        const float inv = 1.f / l_i[r];
        const int q = qt * 64 + w * 16 + quad * 4 + r;
        const size_t ob = (size_t)(tok_off + s * N + q) * 768 + hoff;
        #pragma unroll
        for (int j = 0; j < 4; ++j)
            ao[ob + j * 16 + l4] = __float2bfloat16(oacc[j][r] * inv);
    }
}

// ---------------------------------------------------------------------------
extern "C" void kernel_launch(void* const* d_in, const int* in_sizes, int n_in,
                              void* d_out, int out_size, void* d_ws, size_t ws_size,
                              hipStream_t stream)
{
    const float* x1     = (const float*)d_in[0];
    const float* x2     = (const float*)d_in[1];
    const float* ln1_g  = (const float*)d_in[2];
    const float* ln1_b  = (const float*)d_in[3];
    const float* w_qkv  = (const float*)d_in[4];
    const float* b_qkv  = (const float*)d_in[5];
    const float* w_proj = (const float*)d_in[6];
    const float* b_proj = (const float*)d_in[7];
    const float* ls1    = (const float*)d_in[8];
    const float* ln2_g  = (const float*)d_in[9];
    const float* ln2_b  = (const float*)d_in[10];
    const float* w_fc1  = (const float*)d_in[11];
    const float* b_fc1  = (const float*)d_in[12];
    const float* w_fc2  = (const float*)d_in[13];
    const float* b_fc2  = (const float*)d_in[14];
    const float* ls2    = (const float*)d_in[15];

    char* ws = (char*)d_ws;
    // workspace layout (bytes)
    bf16_t* wqkv_t  = (bf16_t*)(ws + 0);          // 2304x768 bf16
    bf16_t* wproj_t = (bf16_t*)(ws + 3538944);    //  768x768
    bf16_t* wfc1_t  = (bf16_t*)(ws + 4718592);    // 3072x768
    bf16_t* wfc2_t  = (bf16_t*)(ws + 9437184);    //  768x3072
    bf16_t* hbuf    = (bf16_t*)(ws + 14155776);   // 12288x768 bf16 (h, then h2)
    bf16_t* qkvbuf  = (bf16_t*)(ws + 33030144);   // 12288x2304 bf16; later 12288x3072 hidden
    bf16_t* aobuf   = (bf16_t*)(ws + 108527616);  // 12288x768 bf16
    float*  xr      = (float*) (ws + 127401984);  // 12288x768 fp32 residual (end 165150720)

    // 1. weights -> bf16 transposed [N][K]
    wconv_kernel<<<dim3(24, 72), 256, 0, stream>>>(w_qkv,  wqkv_t,  768, 2304);
    wconv_kernel<<<dim3(24, 24), 256, 0, stream>>>(w_proj, wproj_t, 768, 768);
    wconv_kernel<<<dim3(24, 96), 256, 0, stream>>>(w_fc1,  wfc1_t,  768, 3072);
    wconv_kernel<<<dim3(96, 24), 256, 0, stream>>>(w_fc2,  wfc2_t,  3072, 768);

    // 2. residual stream = concat(x1, x2) fp32
    copy_f4_kernel<<<3072, 256, 0, stream>>>((const float4*)x1, (float4*)xr, 786432);
    copy_f4_kernel<<<6144, 256, 0, stream>>>((const float4*)x2, (float4*)(xr + 3145728), 1572864);

    // 3. LN1 -> h (bf16)
    ln_kernel<<<12288, 256, 0, stream>>>(xr, ln1_g, ln1_b, hbuf);

    // 4. qkv = h @ w_qkv + b_qkv  -> bf16 [12288, 2304]
    gemm_kernel<<<dim3(96, 18), 256, 0, stream>>>(hbuf, wqkv_t, b_qkv, nullptr, nullptr,
                                                  qkvbuf, 12288, 2304, 768, 0);

    // 5. attention -> aobuf bf16 [12288, 768]
    attn_kernel<<<dim3(8, 12, 8), 256, 0, stream>>>(qkvbuf, aobuf, 512, 0);
    attn_kernel<<<dim3(16, 12, 8), 256, 0, stream>>>(qkvbuf, aobuf, 1024, 4096);

    // 6. xr += ls1 * (ao @ w_proj + b_proj)   (in place, fp32)
    gemm_kernel<<<dim3(96, 6), 256, 0, stream>>>(aobuf, wproj_t, b_proj, ls1, xr,
                                                 xr, 12288, 768, 768, 2);

    // 7. LN2 -> h2 (bf16, reuse hbuf)
    ln_kernel<<<12288, 256, 0, stream>>>(xr, ln2_g, ln2_b, hbuf);

    // 8. hidden = gelu(h2 @ w_fc1 + b_fc1) -> bf16 [12288, 3072] (reuse qkvbuf)
    gemm_kernel<<<dim3(96, 24), 256, 0, stream>>>(hbuf, wfc1_t, b_fc1, nullptr, nullptr,
                                                  qkvbuf, 12288, 3072, 768, 1);

    // 9. out = xr + ls2 * (hidden @ w_fc2 + b_fc2) -> fp32 d_out
    gemm_kernel<<<dim3(96, 6), 256, 0, stream>>>(qkvbuf, wfc2_t, b_fc2, ls2, xr,
                                                 (float*)d_out, 12288, 768, 3072, 2);
}

// Round 2
// 669.104 us; speedup vs baseline: 1.2994x; 1.2994x over previous
//
#include <hip/hip_runtime.h>
#include <hip/hip_bf16.h>
#include <math.h>

typedef __hip_bfloat16 bf16_t;
typedef __bf16 bf16x8 __attribute__((ext_vector_type(8)));
typedef float f32x4 __attribute__((ext_vector_type(4)));

// ---------------------------------------------------------------------------
// async global->LDS, 16B per lane. LDS dest = wave-uniform base + lane*16.
__device__ __forceinline__ void load_lds16(const void* g, void* l) {
    __builtin_amdgcn_global_load_lds(
        (__attribute__((address_space(1))) void*)g,
        (__attribute__((address_space(3))) void*)l, 16, 0, 0);
}

// ---------------------------------------------------------------------------
// Weight transpose+convert: W [K,N] fp32 -> Wt [N,K] bf16 (B^T layout for GEMM)
__global__ __launch_bounds__(256) void wconv_kernel(
    const float* __restrict__ W, bf16_t* __restrict__ Wt, int K, int N)
{
    __shared__ float tile[32][33];
    const int k0 = blockIdx.x * 32, n0 = blockIdx.y * 32;
    const int tx = threadIdx.x & 31, ty = threadIdx.x >> 5;  // 32x8
    #pragma unroll
    for (int i = 0; i < 32; i += 8)
        tile[ty + i][tx] = W[(size_t)(k0 + ty + i) * N + n0 + tx];
    __syncthreads();
    #pragma unroll
    for (int i = 0; i < 32; i += 8)
        Wt[(size_t)(n0 + ty + i) * K + k0 + tx] = __float2bfloat16(tile[tx][ty + i]);
}

// ---------------------------------------------------------------------------
__global__ __launch_bounds__(256) void copy_f4_kernel(
    const float4* __restrict__ in, float4* __restrict__ out, int n)
{
    const int i = blockIdx.x * 256 + threadIdx.x;
    if (i < n) out[i] = in[i];
}

// ---------------------------------------------------------------------------
// LayerNorm: fp32 row [768] -> bf16 row. One block per token.
__global__ __launch_bounds__(256) void ln_kernel(
    const float* __restrict__ x, const float* __restrict__ g,
    const float* __restrict__ b, bf16_t* __restrict__ out)
{
    const int t = blockIdx.x;
    const int tid = threadIdx.x;
    const float* xr = x + (size_t)t * 768;
    float v[3], s = 0.f, q = 0.f;
    #pragma unroll
    for (int i = 0; i < 3; ++i) {
        v[i] = xr[tid + i * 256];
        s += v[i]; q += v[i] * v[i];
    }
    #pragma unroll
    for (int o = 32; o > 0; o >>= 1) {
        s += __shfl_down(s, o);
        q += __shfl_down(q, o);
    }
    __shared__ float rs_[4], rq_[4];
    const int w = tid >> 6, lane = tid & 63;
    if (lane == 0) { rs_[w] = s; rq_[w] = q; }
    __syncthreads();
    s = rs_[0] + rs_[1] + rs_[2] + rs_[3];
    q = rq_[0] + rq_[1] + rq_[2] + rq_[3];
    const float mean = s * (1.f / 768.f);
    const float var  = q * (1.f / 768.f) - mean * mean;
    const float rstd = rsqrtf(var + 1e-5f);
    bf16_t* orow = out + (size_t)t * 768;
    #pragma unroll
    for (int i = 0; i < 3; ++i) {
        const int d = tid + i * 256;
        orow[d] = __float2bfloat16((v[i] - mean) * rstd * g[d] + b[d]);
    }
}

// ---------------------------------------------------------------------------
// GEMM: C[M,N] = A[M,K] @ B[K,N] (+bias, +epilogue), A bf16 row-major,
// Bt = B^T [N,K] bf16 row-major. 128x128 tile, BK=32, 4 waves of 64x64.
// mode 0: out bf16 = acc+bias
// mode 1: out bf16 = gelu_exact(acc+bias)
// mode 2: out fp32 = resid + ls*(acc+bias)
// mode 3: qkv special: cols<768 -> (acc+bias)*0.125 to qk (stride 1536);
//         cols 768..1535 -> acc+bias to qk; cols>=1536 -> acc+bias to
//         vtout[(col-1536)*12288 + row] (V transposed for attention).
__global__ __launch_bounds__(256) void gemm_kernel(
    const bf16_t* __restrict__ A, const bf16_t* __restrict__ Bt,
    const float* __restrict__ bias, const float* __restrict__ ls,
    const float* __restrict__ resid, void* __restrict__ outp,
    bf16_t* __restrict__ vtout,
    int M, int N, int K, int mode)
{
    __shared__ __align__(16) bf16_t As[128 * 32];
    __shared__ __align__(16) bf16_t Bs[128 * 32];
    const int tid  = threadIdx.x;
    const int lane = tid & 63;
    const int w    = tid >> 6;
    const int wm   = w >> 1, wn = w & 1;
    const int l4   = lane & 15, quad = lane >> 4;
    const int bm   = blockIdx.x, bn = blockIdx.y;

    f32x4 acc[4][4];
    #pragma unroll
    for (int i = 0; i < 4; ++i)
        #pragma unroll
        for (int j = 0; j < 4; ++j)
            #pragma unroll
            for (int e = 0; e < 4; ++e) acc[i][j][e] = 0.f;

    const int srow = lane >> 2;        // 0..15 within a 16-row wave span
    const int scol = (lane & 3) * 8;   // element offset in K
    const bf16_t* Ag = A  + (size_t)(bm * 128) * K;
    const bf16_t* Bg = Bt + (size_t)(bn * 128) * K;

    for (int k0 = 0; k0 < K; k0 += 32) {
        #pragma unroll
        for (int p = 0; p < 2; ++p) {
            const int r = p * 64 + w * 16 + srow;
            load_lds16(Ag + (size_t)r * K + k0 + scol, &As[(p * 64 + w * 16) * 32]);
            load_lds16(Bg + (size_t)r * K + k0 + scol, &Bs[(p * 64 + w * 16) * 32]);
        }
        __syncthreads();
        bf16x8 af[4], bfr[4];
        #pragma unroll
        for (int i = 0; i < 4; ++i)
            af[i] = *(const bf16x8*)&As[(wm * 64 + i * 16 + l4) * 32 + quad * 8];
        #pragma unroll
        for (int j = 0; j < 4; ++j)
            bfr[j] = *(const bf16x8*)&Bs[(wn * 64 + j * 16 + l4) * 32 + quad * 8];
        #pragma unroll
        for (int i = 0; i < 4; ++i)
            #pragma unroll
            for (int j = 0; j < 4; ++j)
                acc[i][j] = __builtin_amdgcn_mfma_f32_16x16x32_bf16(
                    af[i], bfr[j], acc[i][j], 0, 0, 0);
        __syncthreads();
    }

    #pragma unroll
    for (int i = 0; i < 4; ++i) {
        #pragma unroll
        for (int j = 0; j < 4; ++j) {
            const int col  = bn * 128 + wn * 64 + j * 16 + l4;
            const int row0 = bm * 128 + wm * 64 + i * 16 + quad * 4;
            const float bc = bias[col];
            if (mode == 3) {
                if (bn < 12) {                       // Q (scaled) or K
                    const float sc = (bn < 6) ? 0.125f : 1.f;
                    #pragma unroll
                    for (int r = 0; r < 4; ++r)
                        ((bf16_t*)outp)[(size_t)(row0 + r) * 1536 + col] =
                            __float2bfloat16((acc[i][j][r] + bc) * sc);
                } else {                             // V -> transposed
                    bf16_t tmp[4];
                    #pragma unroll
                    for (int r = 0; r < 4; ++r)
                        tmp[r] = __float2bfloat16(acc[i][j][r] + bc);
                    *(float2*)(vtout + (size_t)(col - 1536) * 12288 + row0) =
                        *(const float2*)tmp;
                }
            } else {
                #pragma unroll
                for (int r = 0; r < 4; ++r) {
                    float v = acc[i][j][r] + bc;
                    const size_t idx = (size_t)(row0 + r) * N + col;
                    if (mode == 0) {
                        ((bf16_t*)outp)[idx] = __float2bfloat16(v);
                    } else if (mode == 1) {
                        v = 0.5f * v * (1.f + erff(v * 0.70710678118654752f));
                        ((bf16_t*)outp)[idx] = __float2bfloat16(v);
                    } else {
                        ((float*)outp)[idx] = resid[idx] + ls[col] * v;
                    }
                }
            }
        }
    }
}

// ---------------------------------------------------------------------------
// Flash attention: one block per (seq s, head h, 64-query tile qt).
// qk bf16 [tok][1536]: q (pre-scaled by 1/8) @ h*64, k @ 768+h*64.
// vt bf16 [768][12288]: V transposed, row = h*64+hd, col = global token.
// All staging via async global_load_lds (conflict-free); K/V double-buffered.
__global__ __launch_bounds__(256) void attn_kernel(
    const bf16_t* __restrict__ qk, const bf16_t* __restrict__ vt,
    bf16_t* __restrict__ ao, int N, int tok_off)
{
    __shared__ __align__(16) bf16_t Qs[64 * 64];
    __shared__ __align__(16) bf16_t Kd[2][64 * 64];   // [key][hd]
    __shared__ __align__(16) bf16_t Vd[2][64 * 64];   // [hd][key]
    __shared__ __align__(16) bf16_t Ps[4 * 16 * 64];  // per-wave P scratch / O out
    const int qt = blockIdx.x, h = blockIdx.y, s = blockIdx.z;
    const int tid = threadIdx.x, lane = tid & 63, w = tid >> 6;
    const int l4 = lane & 15, quad = lane >> 4;
    const int seq0 = tok_off + s * N;
    const int hoff = h * 64;
    const int lrow = lane >> 3, lcol = (lane & 7) * 8;  // 8 rows x 128B per instr
    const int nkt = N >> 6;

    // stage Q tile: wave w stages rows [w*16, w*16+16)
    #pragma unroll
    for (int p = 0; p < 2; ++p) {
        const int rr = w * 16 + p * 8;
        load_lds16(qk + (size_t)(seq0 + qt * 64 + rr + lrow) * 1536 + hoff + lcol,
                   &Qs[rr * 64]);
    }

    auto stageKV = [&](int kt, int buf) {
        #pragma unroll
        for (int p = 0; p < 2; ++p) {
            const int rr = w * 16 + p * 8;
            load_lds16(qk + (size_t)(seq0 + kt * 64 + rr + lrow) * 1536 + 768 + hoff + lcol,
                       &Kd[buf][rr * 64]);
            load_lds16(vt + (size_t)(hoff + rr + lrow) * 12288 + seq0 + kt * 64 + lcol,
                       &Vd[buf][rr * 64]);
        }
    };
    stageKV(0, 0);

    f32x4 oacc[4];
    float m_i[4], l_i[4];
    #pragma unroll
    for (int j = 0; j < 4; ++j)
        #pragma unroll
        for (int e = 0; e < 4; ++e) oacc[j][e] = 0.f;
    #pragma unroll
    for (int r = 0; r < 4; ++r) { m_i[r] = -INFINITY; l_i[r] = 0.f; }

    bf16_t* Pw = &Ps[w * 16 * 64];

    for (int kt = 0; kt < nkt; ++kt) {
        const int buf = kt & 1;
        __syncthreads();                   // staged tile kt now visible
        if (kt + 1 < nkt) stageKV(kt + 1, buf ^ 1);   // prefetch (async)

        // S = Q K^T  (16 queries x 64 keys per wave)
        f32x4 st[4];
        #pragma unroll
        for (int j = 0; j < 4; ++j)
            #pragma unroll
            for (int e = 0; e < 4; ++e) st[j][e] = 0.f;
        const bf16x8 aq0 = *(const bf16x8*)&Qs[(w * 16 + l4) * 64 + quad * 8];
        const bf16x8 aq1 = *(const bf16x8*)&Qs[(w * 16 + l4) * 64 + 32 + quad * 8];
        #pragma unroll
        for (int j = 0; j < 4; ++j) {
            const bf16x8 b0 = *(const bf16x8*)&Kd[buf][(j * 16 + l4) * 64 + quad * 8];
            const bf16x8 b1 = *(const bf16x8*)&Kd[buf][(j * 16 + l4) * 64 + 32 + quad * 8];
            st[j] = __builtin_amdgcn_mfma_f32_16x16x32_bf16(aq0, b0, st[j], 0, 0, 0);
            st[j] = __builtin_amdgcn_mfma_f32_16x16x32_bf16(aq1, b1, st[j], 0, 0, 0);
        }

        // online softmax per query row (row = quad*4+r, cols over 16 lanes x 4 tiles)
        float p[4][4];
        #pragma unroll
        for (int r = 0; r < 4; ++r) {
            float mx = fmaxf(fmaxf(st[0][r], st[1][r]), fmaxf(st[2][r], st[3][r]));
            #pragma unroll
            for (int off = 1; off < 16; off <<= 1) mx = fmaxf(mx, __shfl_xor(mx, off));
            const float mnew  = fmaxf(m_i[r], mx);
            const float alpha = __expf(m_i[r] - mnew);
            float rs = 0.f;
            #pragma unroll
            for (int j = 0; j < 4; ++j) { p[j][r] = __expf(st[j][r] - mnew); rs += p[j][r]; }
            #pragma unroll
            for (int off = 1; off < 16; off <<= 1) rs += __shfl_xor(rs, off);
            m_i[r] = mnew;
            l_i[r] = l_i[r] * alpha + rs;
            #pragma unroll
            for (int j = 0; j < 4; ++j) oacc[j][r] *= alpha;
        }

        // P: C-layout -> LDS (wave-private: no barrier needed) -> A-layout
        #pragma unroll
        for (int j = 0; j < 4; ++j)
            #pragma unroll
            for (int r = 0; r < 4; ++r)
                Pw[(quad * 4 + r) * 64 + j * 16 + l4] = __float2bfloat16(p[j][r]);

        const bf16x8 ap0 = *(const bf16x8*)&Pw[l4 * 64 + quad * 8];
        const bf16x8 ap1 = *(const bf16x8*)&Pw[l4 * 64 + 32 + quad * 8];
        #pragma unroll
        for (int j = 0; j < 4; ++j) {
            const bf16x8 v0 = *(const bf16x8*)&Vd[buf][(j * 16 + l4) * 64 + quad * 8];
            const bf16x8 v1 = *(const bf16x8*)&Vd[buf][(j * 16 + l4) * 64 + 32 + quad * 8];
            oacc[j] = __builtin_amdgcn_mfma_f32_16x16x32_bf16(ap0, v0, oacc[j], 0, 0, 0);
            oacc[j] = __builtin_amdgcn_mfma_f32_16x16x32_bf16(ap1, v1, oacc[j], 0, 0, 0);
        }
    }

    // O through LDS (wave-private rows), then vectorized 16B global stores
    #pragma unroll
    for (int r = 0; r < 4; ++r) {
        const float inv = 1.f / l_i[r];
        #pragma unroll
        for (int j = 0; j < 4; ++j)
            Ps[(w * 16 + quad * 4 + r) * 64 + j * 16 + l4] =
                __float2bfloat16(oacc[j][r] * inv);
    }
    __syncthreads();
    #pragma unroll
    for (int p = 0; p < 2; ++p) {
        const int c = p * 256 + tid;          // 512 chunks of 16B
        const int row = c >> 3, c8 = (c & 7) * 8;
        *(float4*)(ao + (size_t)(seq0 + qt * 64 + row) * 768 + hoff + c8) =
            *(const float4*)&Ps[row * 64 + c8];
    }
}

// ---------------------------------------------------------------------------
extern "C" void kernel_launch(void* const* d_in, const int* in_sizes, int n_in,
                              void* d_out, int out_size, void* d_ws, size_t ws_size,
                              hipStream_t stream)
{
    const float* x1     = (const float*)d_in[0];
    const float* x2     = (const float*)d_in[1];
    const float* ln1_g  = (const float*)d_in[2];
    const float* ln1_b  = (const float*)d_in[3];
    const float* w_qkv  = (const float*)d_in[4];
    const float* b_qkv  = (const float*)d_in[5];
    const float* w_proj = (const float*)d_in[6];
    const float* b_proj = (const float*)d_in[7];
    const float* ls1    = (const float*)d_in[8];
    const float* ln2_g  = (const float*)d_in[9];
    const float* ln2_b  = (const float*)d_in[10];
    const float* w_fc1  = (const float*)d_in[11];
    const float* b_fc1  = (const float*)d_in[12];
    const float* w_fc2  = (const float*)d_in[13];
    const float* b_fc2  = (const float*)d_in[14];
    const float* ls2    = (const float*)d_in[15];

    char* ws = (char*)d_ws;
    // workspace layout (bytes) — total 165,150,720 (same as R1)
    bf16_t* wqkv_t  = (bf16_t*)(ws + 0);           // 2304x768 bf16
    bf16_t* wproj_t = (bf16_t*)(ws + 3538944);     //  768x768
    bf16_t* wfc1_t  = (bf16_t*)(ws + 4718592);     // 3072x768
    bf16_t* wfc2_t  = (bf16_t*)(ws + 9437184);     //  768x3072
    bf16_t* hbuf    = (bf16_t*)(ws + 14155776);    // 12288x768 bf16 (h, then h2)
    bf16_t* qkbuf   = (bf16_t*)(ws + 33030144);    // 12288x1536 bf16 (Q|K)
    bf16_t* vtbuf   = (bf16_t*)(ws + 70778880);    // 768x12288 bf16 (V^T)
    // fc1 hidden [12288x3072] bf16 reuses qkbuf..vtbuf end (attention dead by then)
    bf16_t* hidbuf  = (bf16_t*)(ws + 33030144);
    bf16_t* aobuf   = (bf16_t*)(ws + 108527616);   // 12288x768 bf16
    float*  xr      = (float*) (ws + 127401984);   // 12288x768 fp32 residual

    // 1. weights -> bf16 transposed [N][K]
    wconv_kernel<<<dim3(24, 72), 256, 0, stream>>>(w_qkv,  wqkv_t,  768, 2304);
    wconv_kernel<<<dim3(24, 24), 256, 0, stream>>>(w_proj, wproj_t, 768, 768);
    wconv_kernel<<<dim3(24, 96), 256, 0, stream>>>(w_fc1,  wfc1_t,  768, 3072);
    wconv_kernel<<<dim3(96, 24), 256, 0, stream>>>(w_fc2,  wfc2_t,  3072, 768);

    // 2. residual stream = concat(x1, x2) fp32
    copy_f4_kernel<<<3072, 256, 0, stream>>>((const float4*)x1, (float4*)xr, 786432);
    copy_f4_kernel<<<6144, 256, 0, stream>>>((const float4*)x2, (float4*)(xr + 3145728), 1572864);

    // 3. LN1 -> h (bf16)
    ln_kernel<<<12288, 256, 0, stream>>>(xr, ln1_g, ln1_b, hbuf);

    // 4. qkv GEMM: Q (x0.125) | K -> qkbuf [12288,1536]; V -> vtbuf [768,12288]
    gemm_kernel<<<dim3(96, 18), 256, 0, stream>>>(hbuf, wqkv_t, b_qkv, nullptr, nullptr,
                                                  qkbuf, vtbuf, 12288, 2304, 768, 3);

    // 5. attention -> aobuf bf16 [12288, 768]
    attn_kernel<<<dim3(8, 12, 8), 256, 0, stream>>>(qkbuf, vtbuf, aobuf, 512, 0);
    attn_kernel<<<dim3(16, 12, 8), 256, 0, stream>>>(qkbuf, vtbuf, aobuf, 1024, 4096);

    // 6. xr += ls1 * (ao @ w_proj + b_proj)   (in place, fp32)
    gemm_kernel<<<dim3(96, 6), 256, 0, stream>>>(aobuf, wproj_t, b_proj, ls1, xr,
                                                 xr, nullptr, 12288, 768, 768, 2);

    // 7. LN2 -> h2 (bf16, reuse hbuf)
    ln_kernel<<<12288, 256, 0, stream>>>(xr, ln2_g, ln2_b, hbuf);

    // 8. hidden = gelu(h2 @ w_fc1 + b_fc1) -> bf16 [12288, 3072]
    gemm_kernel<<<dim3(96, 24), 256, 0, stream>>>(hbuf, wfc1_t, b_fc1, nullptr, nullptr,
                                                  hidbuf, nullptr, 12288, 3072, 768, 1);

    // 9. out = xr + ls2 * (hidden @ w_fc2 + b_fc2) -> fp32 d_out
    gemm_kernel<<<dim3(96, 6), 256, 0, stream>>>(hidbuf, wfc2_t, b_fc2, ls2, xr,
                                                 (float*)d_out, nullptr, 12288, 768, 3072, 2);
}